// Round 5
// baseline (4469.320 us; speedup 1.0000x reference)
//
#include <hip/hip_runtime.h>

#define Tn 1024
#define Bn 64
#define In_ 64
#define Hn 512
#define On 64
#define DTC 0.5f

typedef __attribute__((ext_vector_type(8))) short short8;   // bf16x8 MFMA frag
typedef __attribute__((ext_vector_type(4))) short short4v;  // bf16x4 (8B)
typedef __attribute__((ext_vector_type(4))) float floatx4;  // MFMA C frag
typedef unsigned long long u64;

__device__ __forceinline__ float bf2f(unsigned short u){
  union{unsigned int i; float f;} v; v.i = ((unsigned int)u)<<16; return v.f;
}
__device__ __forceinline__ unsigned short f2bf(float f){   // RNE
  union{float f; unsigned int i;} v; v.f=f;
  unsigned int x=v.i;
  return (unsigned short)((x + 0x7fffu + ((x>>16)&1u))>>16);
}
__device__ __forceinline__ short8 cvt8(const float* p){
  short8 v;
  #pragma unroll
  for (int e=0;e<8;e++) v[e] = (short)f2bf(p[e]);
  return v;
}
// raw LDS-only barrier: no vmcnt(0) drain (global stores keep flying)
__device__ __forceinline__ void barrier_lds(){
  asm volatile("s_waitcnt lgkmcnt(0)\n\ts_barrier" ::: "memory");
}
// pinned load: volatile asm can't be rematerialized/sunk into the loop.
// waitcnt inside the same asm so the result regs are safe at C level.
__device__ __forceinline__ short8 gload16(const unsigned short* p){
  short8 r;
  asm volatile("global_load_dwordx4 %0, %1, off\n\ts_waitcnt vmcnt(0)"
               : "=&v"(r) : "v"(p) : "memory");
  return r;
}

// ---------------- xproj: xp[t][b][j] = inp[b][t][:]@wi[:,j] + brec[j] (bf16) --------
__global__ __launch_bounds__(256,2) void xproj_kernel(
    const float* __restrict__ inp, const float* __restrict__ wi,
    const float* __restrict__ brec, unsigned short* __restrict__ xp)
{
  const int t = blockIdx.x, tid = threadIdx.x;
  const int wv = tid>>6, lane = tid&63, col = lane&15, quad = lane>>4;
  __shared__ __align__(16) unsigned short inA[64*80];   // [b][i], pad 80
  {
    int r = tid>>2, i0 = (tid&3)*16;
    const float* src = inp + ((size_t)r*Tn + t)*In_ + i0;
    unsigned short tmp[16];
    #pragma unroll
    for (int q=0;q<16;q++) tmp[q] = f2bf(src[q]);
    *(short8*)&inA[r*80 + i0]     = *(short8*)&tmp[0];
    *(short8*)&inA[r*80 + i0 + 8] = *(short8*)&tmp[8];
  }
  const int wnb = wv*128;
  short8 bw[8][2];
  float brecv[8];
  #pragma unroll
  for (int nt=0;nt<8;nt++){
    int j = wnb + nt*16 + col;
    brecv[nt] = brec[j];
    #pragma unroll
    for (int ks=0;ks<2;ks++){
      float tmp[8];
      #pragma unroll
      for (int e=0;e<8;e++) tmp[e] = wi[(size_t)(ks*32 + quad*8 + e)*Hn + j];
      bw[nt][ks] = cvt8(tmp);
    }
  }
  __syncthreads();
  floatx4 acc[4][8];
  #pragma unroll
  for (int mt=0;mt<4;mt++)
    #pragma unroll
    for (int nt=0;nt<8;nt++) acc[mt][nt] = (floatx4){0.f,0.f,0.f,0.f};
  #pragma unroll
  for (int ks=0;ks<2;ks++)
    #pragma unroll
    for (int mt=0;mt<4;mt++){
      short8 ar = *(const short8*)&inA[(mt*16+col)*80 + ks*32 + quad*8];
      #pragma unroll
      for (int nt=0;nt<8;nt++)
        acc[mt][nt] = __builtin_amdgcn_mfma_f32_16x16x32_bf16(ar, bw[nt][ks], acc[mt][nt],0,0,0);
    }
  #pragma unroll
  for (int mt=0;mt<4;mt++)
    #pragma unroll
    for (int nt=0;nt<8;nt++)
      #pragma unroll
      for (int r=0;r<4;r++){
        int b = mt*16 + quad*4 + r;
        int j = wnb + nt*16 + col;
        xp[((size_t)t*Bn + b)*Hn + j] = f2bf(acc[mt][nt][r] + brecv[nt]);
      }
}

// ---- wrec_pack: ALL of wrec -> bf16 A-frags in scan's exact read order (512 KB) ----
// frag f = (wv*4+mt)*16 + ks ; element (f*64+lane)*8 ; j=wv*64+mt*16+(lane&15),
// k = ks*32+(lane>>4)*8
__global__ __launch_bounds__(256,1) void wrec_pack(
    const float* __restrict__ wrec, unsigned short* __restrict__ wrecP)
{
  int gl = blockIdx.x*256 + threadIdx.x;      // 0..32767
  int frag = gl>>6, lane = gl&63;
  int wvmt = frag>>4, ks = frag&15;
  int j = (wvmt>>2)*64 + (wvmt&3)*16 + (lane&15);
  int k = ks*32 + (lane>>4)*8;
  short8 v = cvt8(wrec + (size_t)j*Hn + k);
  *(short8*)(wrecP + (size_t)gl*8) = v;
}

// ------------- scan: 4 blocks x 512 threads; one CU per 16-batch group --------------
// Transposed compute: pre^T[j][b] = sum_k wrec[j][k] h[b][k].
// A=wrec: ks 0..11 PINNED in VGPRs (asm loads, 192 regs), ks 12..15 in LDS (128KB).
// Zero per-step weight traffic. B=h: bf16 frag layout in LDS (16KB); fp32 master
// in registers. Sync = 2 LDS-only barriers/step. Zero cross-block traffic.
__global__ __launch_bounds__(512,2) void rnn_scan(
    const float* __restrict__ h0,
    const unsigned short* xp,            // ws+64KB  [T][B][H] bf16 (aliases hs+1 slot)
    const unsigned short* __restrict__ wrecP,
    unsigned short* hs)                  // ws       [T][B][H] bf16
{
  const int tid  = threadIdx.x;
  const int g    = blockIdx.x;          // batch group: b in [16g, 16g+16)
  const int wv   = tid >> 6;            // 0..7, owns j in [64wv, 64wv+64)
  const int lane = tid & 63;
  const int col  = lane & 15;
  const int quad = lane >> 4;
  const int wbase = wv*64;

  __shared__ __align__(16) unsigned short wrecL[65536]; // 128KB: ((wv*4+mt)*4+ks2)*512+lane*8
  __shared__ __align__(16) unsigned short hA[8192];     // 16KB:  ks*512+lane*8

  // A-frags ks 0..11 -> pinned registers (48 frags, 192 VGPR). Pre-packed bf16,
  // loaded via volatile asm so the allocator cannot remat them into the loop.
  short8 awr[48];
  #pragma unroll
  for (int mt=0;mt<4;mt++)
    #pragma unroll
    for (int ks=0;ks<12;ks++)
      awr[mt*12+ks] = gload16(wrecP + (size_t)(((wv*4+mt)*16 + ks)*64 + lane)*8);

  // A-frags ks 12..15 -> LDS (from packed buffer, no cvt)
  #pragma unroll
  for (int mt=0;mt<4;mt++)
    #pragma unroll
    for (int ks2=0;ks2<4;ks2++)
      *(short8*)&wrecL[(((wv*4+mt)*4 + ks2))*512 + lane*8] =
        *(const short8*)(wrecP + (size_t)(((wv*4+mt)*16 + 12 + ks2)*64 + lane)*8);

  // h0 -> hA (bf16 frag layout: (b,k) at ((k>>5)*64+((k>>3)&3)*16+b)*8+(k&7))
  for (int idx = tid; idx < 16*Hn; idx += 512){
    int b = idx >> 9, k = idx & 511;
    hA[(((k>>5)*64 + ((k>>3)&3)*16 + b))*8 + (k&7)] = f2bf(h0[k]);
  }
  // fp32 h master: lane owns (b=col, j = wbase+mt*16+quad*4+r)
  float hm[4][4];
  #pragma unroll
  for (int mt=0;mt<4;mt++)
    #pragma unroll
    for (int r=0;r<4;r++) hm[mt][r] = h0[wbase + mt*16 + quad*4 + r];

  floatx4 acc[4];
  #pragma unroll
  for (int mt=0;mt<4;mt++) acc[mt] = (floatx4){0.f,0.f,0.f,0.f};

  const size_t row = (size_t)(g*16 + col);   // global batch for this lane
  const unsigned short* xpp = xp + row*Hn + wbase;      // advances 64KB/step
  unsigned short* hsp = hs + row*Hn + wbase;            // advances 64KB/step
  __syncthreads();

  for (int t = 0; t < Tn; t++){
    // prefetch xproj for this step (global, consumed ~700 cyc later)
    u64 xv[4];
    #pragma unroll
    for (int mt=0;mt<4;mt++)
      xv[mt] = *(const u64*)(xpp + mt*16 + quad*4);

    // K-sweep: ks 0..11 from pinned regs, ks 12..15 from LDS
    #pragma unroll
    for (int ks=0;ks<12;ks++){
      short8 hb = *(const short8*)&hA[ks*512 + lane*8];
      #pragma unroll
      for (int mt=0;mt<4;mt++)
        acc[mt] = __builtin_amdgcn_mfma_f32_16x16x32_bf16(awr[mt*12+ks], hb, acc[mt],0,0,0);
    }
    #pragma unroll
    for (int ks2=0;ks2<4;ks2++){
      short8 hb = *(const short8*)&hA[(12+ks2)*512 + lane*8];
      #pragma unroll
      for (int mt=0;mt<4;mt++){
        short8 aw = *(const short8*)&wrecL[(((wv*4+mt)*4 + ks2))*512 + lane*8];
        acc[mt] = __builtin_amdgcn_mfma_f32_16x16x32_bf16(aw, hb, acc[mt],0,0,0);
      }
    }

    barrier_lds();   // all hA reads done CU-wide before epilogue rewrites hA

    // epilogue: lane owns (b=col, 16 j's); C layout row=j(quad*4+r), col=b
    #pragma unroll
    for (int mt=0;mt<4;mt++){
      u64 x = xv[mt];
      unsigned short hv[4];
      #pragma unroll
      for (int r=0;r<4;r++){
        float pre = acc[mt][r] + bf2f((unsigned short)(x >> (16*r)));
        float e2x = __expf(2.0f*pre);
        float rec = 1.0f - 2.0f/(e2x + 1.0f);       // tanh, robust at +-inf
        float hn  = (1.0f-DTC)*hm[mt][r] + DTC*rec;
        hm[mt][r] = hn;
        hv[r] = f2bf(hn);
      }
      int j4 = wbase + mt*16 + quad*4;
      *(short4v*)&hA[(((j4>>5)*64 + ((j4>>3)&3)*16 + col))*8 + (j4&7)] = *(short4v*)hv;
      u64 pk = (u64)hv[0] | ((u64)hv[1]<<16) | ((u64)hv[2]<<32) | ((u64)hv[3]<<48);
      __builtin_nontemporal_store(pk, (u64*)(hsp + mt*16 + quad*4));
      acc[mt] = (floatx4){0.f,0.f,0.f,0.f};
    }
    xpp += Bn*Hn;
    hsp += Bn*Hn;
    barrier_lds();   // hA(t+1) visible before next step's reads
  }
}

// ------------- out: out[b][t][o] = hs[t][b][:] @ wo ; rows m = t*64+b ---------------
__global__ __launch_bounds__(256,1) void out_gemm(
    const unsigned short* __restrict__ hs,
    const float* __restrict__ wo,
    float* __restrict__ out)
{
  const int tid = threadIdx.x, bid = blockIdx.x;
  const int wv = tid >> 6, lane = tid & 63, col = lane & 15, quad = lane >> 4;
  const int m0 = bid*64;
  __shared__ __align__(16) unsigned short hsA[64][520];

  for (int c = tid; c < 64*64; c += 256){
    int r = c >> 6, cc = (c & 63)*8;
    *(short8*)&hsA[r][cc] = *(const short8*)(hs + (size_t)(m0 + r)*Hn + cc);
  }
  short8 boh[16], bol[16];
  #pragma unroll
  for (int kk = 0; kk < 16; kk++){
    float tmp[8];
    #pragma unroll
    for (int e = 0; e < 8; e++) tmp[e] = wo[(size_t)(kk*32 + quad*8 + e)*On + wv*16 + col];
    #pragma unroll
    for (int e = 0; e < 8; e++){
      unsigned short h = f2bf(tmp[e]);
      boh[kk][e] = (short)h;
      bol[kk][e] = (short)f2bf(tmp[e] - bf2f(h));
    }
  }
  __syncthreads();

  floatx4 acc[4];
  #pragma unroll
  for (int ms=0;ms<4;ms++) acc[ms] = (floatx4){0.f,0.f,0.f,0.f};
  #pragma unroll
  for (int kk = 0; kk < 16; kk++){
    int k = kk*32 + quad*8;
    #pragma unroll
    for (int ms = 0; ms < 4; ms++){
      short8 a = *(const short8*)&hsA[ms*16 + col][k];
      acc[ms] = __builtin_amdgcn_mfma_f32_16x16x32_bf16(a, boh[kk], acc[ms], 0,0,0);
      acc[ms] = __builtin_amdgcn_mfma_f32_16x16x32_bf16(a, bol[kk], acc[ms], 0,0,0);
    }
  }
  #pragma unroll
  for (int ms = 0; ms < 4; ms++)
    #pragma unroll
    for (int r = 0; r < 4; r++){
      int m = m0 + ms*16 + quad*4 + r;     // m = t*64 + b
      int b = m & 63, tt = m >> 6;
      out[((size_t)b*Tn + tt)*On + wv*16 + col] = acc[ms][r];
    }
}

extern "C" void kernel_launch(void* const* d_in, const int* in_sizes, int n_in,
                              void* d_out, int out_size, void* d_ws, size_t ws_size,
                              hipStream_t stream){
  const float* inp  = (const float*)d_in[0];
  const float* wi   = (const float*)d_in[1];
  const float* wrec = (const float*)d_in[2];
  const float* wo   = (const float*)d_in[3];
  const float* brec = (const float*)d_in[4];
  const float* h0   = (const float*)d_in[5];
  float* out = (float*)d_out;

  char* ws = (char*)d_ws;
  // hs slots: ws + t*64KB. xp slots: ws + 64KB + t*64KB (= hs slot t+1).
  // Scan step t writes hs[t] (destroys xp[t-1], already consumed; per-group
  // b-slices disjoint, so cross-block skew is safe). wrecP after: 512 KB.
  unsigned short* hs = (unsigned short*)ws;
  unsigned short* xp = (unsigned short*)(ws + 65536);
  unsigned short* wrecP = (unsigned short*)(ws + (size_t)Tn*Bn*Hn*2 + 65536);

  xproj_kernel<<<Tn, 256, 0, stream>>>(inp, wi, brec, xp);
  wrec_pack  <<<128, 256, 0, stream>>>(wrec, wrecP);
  rnn_scan   <<<4, 512, 0, stream>>>(h0, xp, wrecP, hs);
  out_gemm   <<<(Bn*Tn)/64, 256, 0, stream>>>(hs, wo, out);
}

// Round 6
// 4450.502 us; speedup vs baseline: 1.0042x; 1.0042x over previous
//
#include <hip/hip_runtime.h>

#define Tn 1024
#define Bn 64
#define In_ 64
#define Hn 512
#define On 64
#define DTC 0.5f

typedef __attribute__((ext_vector_type(8))) short short8;   // bf16x8 MFMA frag
typedef __attribute__((ext_vector_type(4))) short short4v;  // bf16x4 (8B)
typedef __attribute__((ext_vector_type(4))) float floatx4;  // MFMA C frag
typedef unsigned long long u64;

__device__ __forceinline__ float bf2f(unsigned short u){
  union{unsigned int i; float f;} v; v.i = ((unsigned int)u)<<16; return v.f;
}
__device__ __forceinline__ unsigned short f2bf(float f){   // RNE
  union{float f; unsigned int i;} v; v.f=f;
  unsigned int x=v.i;
  return (unsigned short)((x + 0x7fffu + ((x>>16)&1u))>>16);
}
__device__ __forceinline__ short8 cvt8(const float* p){
  short8 v;
  #pragma unroll
  for (int e=0;e<8;e++) v[e] = (short)f2bf(p[e]);
  return v;
}
// raw LDS-only barrier: no vmcnt(0) drain (global stores keep flying)
__device__ __forceinline__ void barrier_lds(){
  asm volatile("s_waitcnt lgkmcnt(0)\n\ts_barrier" ::: "memory");
}
// pinned load: volatile asm can't be rematerialized/sunk into the loop.
__device__ __forceinline__ short8 gload16(const unsigned short* p){
  short8 r;
  asm volatile("global_load_dwordx4 %0, %1, off\n\ts_waitcnt vmcnt(0)"
               : "=&v"(r) : "v"(p) : "memory");
  return r;
}

// ---------------- xproj: xp[t][b][j] = inp[b][t][:]@wi[:,j] + brec[j] (bf16) --------
__global__ __launch_bounds__(256,2) void xproj_kernel(
    const float* __restrict__ inp, const float* __restrict__ wi,
    const float* __restrict__ brec, unsigned short* __restrict__ xp)
{
  const int t = blockIdx.x, tid = threadIdx.x;
  const int wv = tid>>6, lane = tid&63, col = lane&15, quad = lane>>4;
  __shared__ __align__(16) unsigned short inA[64*80];   // [b][i], pad 80
  {
    int r = tid>>2, i0 = (tid&3)*16;
    const float* src = inp + ((size_t)r*Tn + t)*In_ + i0;
    unsigned short tmp[16];
    #pragma unroll
    for (int q=0;q<16;q++) tmp[q] = f2bf(src[q]);
    *(short8*)&inA[r*80 + i0]     = *(short8*)&tmp[0];
    *(short8*)&inA[r*80 + i0 + 8] = *(short8*)&tmp[8];
  }
  const int wnb = wv*128;
  short8 bw[8][2];
  float brecv[8];
  #pragma unroll
  for (int nt=0;nt<8;nt++){
    int j = wnb + nt*16 + col;
    brecv[nt] = brec[j];
    #pragma unroll
    for (int ks=0;ks<2;ks++){
      float tmp[8];
      #pragma unroll
      for (int e=0;e<8;e++) tmp[e] = wi[(size_t)(ks*32 + quad*8 + e)*Hn + j];
      bw[nt][ks] = cvt8(tmp);
    }
  }
  __syncthreads();
  floatx4 acc[4][8];
  #pragma unroll
  for (int mt=0;mt<4;mt++)
    #pragma unroll
    for (int nt=0;nt<8;nt++) acc[mt][nt] = (floatx4){0.f,0.f,0.f,0.f};
  #pragma unroll
  for (int ks=0;ks<2;ks++)
    #pragma unroll
    for (int mt=0;mt<4;mt++){
      short8 ar = *(const short8*)&inA[(mt*16+col)*80 + ks*32 + quad*8];
      #pragma unroll
      for (int nt=0;nt<8;nt++)
        acc[mt][nt] = __builtin_amdgcn_mfma_f32_16x16x32_bf16(ar, bw[nt][ks], acc[mt][nt],0,0,0);
    }
  #pragma unroll
  for (int mt=0;mt<4;mt++)
    #pragma unroll
    for (int nt=0;nt<8;nt++)
      #pragma unroll
      for (int r=0;r<4;r++){
        int b = mt*16 + quad*4 + r;
        int j = wnb + nt*16 + col;
        xp[((size_t)t*Bn + b)*Hn + j] = f2bf(acc[mt][nt][r] + brecv[nt]);
      }
}

// ---- wrec_pack: ALL of wrec -> bf16 A-frags in scan's exact read order (512 KB) ----
__global__ __launch_bounds__(256,1) void wrec_pack(
    const float* __restrict__ wrec, unsigned short* __restrict__ wrecP)
{
  int gl = blockIdx.x*256 + threadIdx.x;      // 0..32767
  int frag = gl>>6, lane = gl&63;
  int wvmt = frag>>4, ks = frag&15;
  int j = (wvmt>>2)*64 + (wvmt&3)*16 + (lane&15);
  int k = ks*32 + (lane>>4)*8;
  short8 v = cvt8(wrec + (size_t)j*Hn + k);
  *(short8*)(wrecP + (size_t)gl*8) = v;
}

// ------------- scan: 4 blocks x 512 threads; one CU per 16-batch group --------------
// Transposed compute: pre^T[j][b] = sum_k wrec[j][k] h[b][k].
// A=wrec: ks 0..11 PINNED in VGPRs (asm loads, 192 regs), ks 12..15 in LDS (128KB).
// VGPR cap raised to 256 via waves_per_eu(2,2): a 512-thread block needs exactly
// 2 waves/SIMD, so 256 is the legal max. (R5 post-mortem: __launch_bounds__(512,2)
// capped at 128 -> awr spilled to scratch, per-step scratch reloads.)
__global__ __launch_bounds__(512)
__attribute__((amdgpu_waves_per_eu(2, 2)))
void rnn_scan(
    const float* __restrict__ h0,
    const unsigned short* xp,            // ws+64KB  [T][B][H] bf16 (aliases hs+1 slot)
    const unsigned short* __restrict__ wrecP,
    unsigned short* hs)                  // ws       [T][B][H] bf16
{
  const int tid  = threadIdx.x;
  const int g    = blockIdx.x;          // batch group: b in [16g, 16g+16)
  const int wv   = tid >> 6;            // 0..7, owns j in [64wv, 64wv+64)
  const int lane = tid & 63;
  const int col  = lane & 15;
  const int quad = lane >> 4;
  const int wbase = wv*64;

  __shared__ __align__(16) unsigned short wrecL[65536]; // 128KB: ((wv*4+mt)*4+ks2)*512+lane*8
  __shared__ __align__(16) unsigned short hA[8192];     // 16KB:  ks*512+lane*8

  // A-frags ks 0..11 -> pinned registers (48 frags, 192 VGPR).
  short8 awr[48];
  #pragma unroll
  for (int mt=0;mt<4;mt++)
    #pragma unroll
    for (int ks=0;ks<12;ks++)
      awr[mt*12+ks] = gload16(wrecP + (size_t)(((wv*4+mt)*16 + ks)*64 + lane)*8);

  // A-frags ks 12..15 -> LDS (from packed buffer, no cvt)
  #pragma unroll
  for (int mt=0;mt<4;mt++)
    #pragma unroll
    for (int ks2=0;ks2<4;ks2++)
      *(short8*)&wrecL[(((wv*4+mt)*4 + ks2))*512 + lane*8] =
        *(const short8*)(wrecP + (size_t)(((wv*4+mt)*16 + 12 + ks2)*64 + lane)*8);

  // h0 -> hA (bf16 frag layout: (b,k) at ((k>>5)*64+((k>>3)&3)*16+b)*8+(k&7))
  for (int idx = tid; idx < 16*Hn; idx += 512){
    int b = idx >> 9, k = idx & 511;
    hA[(((k>>5)*64 + ((k>>3)&3)*16 + b))*8 + (k&7)] = f2bf(h0[k]);
  }
  // fp32 h master: lane owns (b=col, j = wbase+mt*16+quad*4+r)
  float hm[4][4];
  #pragma unroll
  for (int mt=0;mt<4;mt++)
    #pragma unroll
    for (int r=0;r<4;r++) hm[mt][r] = h0[wbase + mt*16 + quad*4 + r];

  floatx4 acc[4];
  #pragma unroll
  for (int mt=0;mt<4;mt++) acc[mt] = (floatx4){0.f,0.f,0.f,0.f};

  const size_t row = (size_t)(g*16 + col);   // global batch for this lane
  const unsigned short* xpp = xp + row*Hn + wbase;      // advances 64KB/step
  unsigned short* hsp = hs + row*Hn + wbase;            // advances 64KB/step
  __syncthreads();

  for (int t = 0; t < Tn; t++){
    // prefetch xproj for this step (global, consumed ~700 cyc later)
    u64 xv[4];
    #pragma unroll
    for (int mt=0;mt<4;mt++)
      xv[mt] = *(const u64*)(xpp + mt*16 + quad*4);

    // K-sweep: ks 0..11 from pinned regs, ks 12..15 from LDS
    #pragma unroll
    for (int ks=0;ks<12;ks++){
      short8 hb = *(const short8*)&hA[ks*512 + lane*8];
      #pragma unroll
      for (int mt=0;mt<4;mt++)
        acc[mt] = __builtin_amdgcn_mfma_f32_16x16x32_bf16(awr[mt*12+ks], hb, acc[mt],0,0,0);
    }
    #pragma unroll
    for (int ks2=0;ks2<4;ks2++){
      short8 hb = *(const short8*)&hA[(12+ks2)*512 + lane*8];
      #pragma unroll
      for (int mt=0;mt<4;mt++){
        short8 aw = *(const short8*)&wrecL[(((wv*4+mt)*4 + ks2))*512 + lane*8];
        acc[mt] = __builtin_amdgcn_mfma_f32_16x16x32_bf16(aw, hb, acc[mt],0,0,0);
      }
    }

    barrier_lds();   // all hA reads done CU-wide before epilogue rewrites hA

    // epilogue: lane owns (b=col, 16 j's); C layout row=j(quad*4+r), col=b
    #pragma unroll
    for (int mt=0;mt<4;mt++){
      u64 x = xv[mt];
      unsigned short hv[4];
      #pragma unroll
      for (int r=0;r<4;r++){
        float pre = acc[mt][r] + bf2f((unsigned short)(x >> (16*r)));
        float e2x = __expf(2.0f*pre);
        float rec = 1.0f - 2.0f/(e2x + 1.0f);       // tanh, robust at +-inf
        float hn  = (1.0f-DTC)*hm[mt][r] + DTC*rec;
        hm[mt][r] = hn;
        hv[r] = f2bf(hn);
      }
      int j4 = wbase + mt*16 + quad*4;
      *(short4v*)&hA[(((j4>>5)*64 + ((j4>>3)&3)*16 + col))*8 + (j4&7)] = *(short4v*)hv;
      u64 pk = (u64)hv[0] | ((u64)hv[1]<<16) | ((u64)hv[2]<<32) | ((u64)hv[3]<<48);
      __builtin_nontemporal_store(pk, (u64*)(hsp + mt*16 + quad*4));
      acc[mt] = (floatx4){0.f,0.f,0.f,0.f};
    }
    xpp += Bn*Hn;
    hsp += Bn*Hn;
    barrier_lds();   // hA(t+1) visible before next step's reads
  }
}

// ------------- out: out[b][t][o] = hs[t][b][:] @ wo ; rows m = t*64+b ---------------
__global__ __launch_bounds__(256,1) void out_gemm(
    const unsigned short* __restrict__ hs,
    const float* __restrict__ wo,
    float* __restrict__ out)
{
  const int tid = threadIdx.x, bid = blockIdx.x;
  const int wv = tid >> 6, lane = tid & 63, col = lane & 15, quad = lane >> 4;
  const int m0 = bid*64;
  __shared__ __align__(16) unsigned short hsA[64][520];

  for (int c = tid; c < 64*64; c += 256){
    int r = c >> 6, cc = (c & 63)*8;
    *(short8*)&hsA[r][cc] = *(const short8*)(hs + (size_t)(m0 + r)*Hn + cc);
  }
  short8 boh[16], bol[16];
  #pragma unroll
  for (int kk = 0; kk < 16; kk++){
    float tmp[8];
    #pragma unroll
    for (int e = 0; e < 8; e++) tmp[e] = wo[(size_t)(kk*32 + quad*8 + e)*On + wv*16 + col];
    #pragma unroll
    for (int e = 0; e < 8; e++){
      unsigned short h = f2bf(tmp[e]);
      boh[kk][e] = (short)h;
      bol[kk][e] = (short)f2bf(tmp[e] - bf2f(h));
    }
  }
  __syncthreads();

  floatx4 acc[4];
  #pragma unroll
  for (int ms=0;ms<4;ms++) acc[ms] = (floatx4){0.f,0.f,0.f,0.f};
  #pragma unroll
  for (int kk = 0; kk < 16; kk++){
    int k = kk*32 + quad*8;
    #pragma unroll
    for (int ms = 0; ms < 4; ms++){
      short8 a = *(const short8*)&hsA[ms*16 + col][k];
      acc[ms] = __builtin_amdgcn_mfma_f32_16x16x32_bf16(a, boh[kk], acc[ms], 0,0,0);
      acc[ms] = __builtin_amdgcn_mfma_f32_16x16x32_bf16(a, bol[kk], acc[ms], 0,0,0);
    }
  }
  #pragma unroll
  for (int ms = 0; ms < 4; ms++)
    #pragma unroll
    for (int r = 0; r < 4; r++){
      int m = m0 + ms*16 + quad*4 + r;     // m = t*64 + b
      int b = m & 63, tt = m >> 6;
      out[((size_t)b*Tn + tt)*On + wv*16 + col] = acc[ms][r];
    }
}

extern "C" void kernel_launch(void* const* d_in, const int* in_sizes, int n_in,
                              void* d_out, int out_size, void* d_ws, size_t ws_size,
                              hipStream_t stream){
  const float* inp  = (const float*)d_in[0];
  const float* wi   = (const float*)d_in[1];
  const float* wrec = (const float*)d_in[2];
  const float* wo   = (const float*)d_in[3];
  const float* brec = (const float*)d_in[4];
  const float* h0   = (const float*)d_in[5];
  float* out = (float*)d_out;

  char* ws = (char*)d_ws;
  // hs slots: ws + t*64KB. xp slots: ws + 64KB + t*64KB (= hs slot t+1).
  // Scan step t writes hs[t] (destroys xp[t-1], already consumed; per-group
  // b-slices disjoint, so cross-block skew is safe). wrecP after: 512 KB.
  unsigned short* hs = (unsigned short*)ws;
  unsigned short* xp = (unsigned short*)(ws + 65536);
  unsigned short* wrecP = (unsigned short*)(ws + (size_t)Tn*Bn*Hn*2 + 65536);

  xproj_kernel<<<Tn, 256, 0, stream>>>(inp, wi, brec, xp);
  wrec_pack  <<<128, 256, 0, stream>>>(wrec, wrecP);
  rnn_scan   <<<4, 512, 0, stream>>>(h0, xp, wrecP, hs);
  out_gemm   <<<(Bn*Tn)/64, 256, 0, stream>>>(hs, wo, out);
}